// Round 8
// baseline (2226.481 us; speedup 1.0000x reference)
//
#include <hip/hip_runtime.h>
#include <stdint.h>

#define N_TOK 8192
#define HDIM  1024
#define NEXP  8
#define CAP   16384   // per-expert rowid list capacity
#define MAXT256 72    // >= sum_e ceil(ce/256) = 64 + 7 max

typedef __bf16 bf16x8 __attribute__((ext_vector_type(8)));
typedef float  f32x4  __attribute__((ext_vector_type(4)));

__device__ inline unsigned short f2bf(float f) {
  union { float f; unsigned u; } v; v.f = f;
  return (unsigned short)((v.u + 0x7fffu + ((v.u >> 16) & 1u)) >> 16);  // RNE
}

__device__ inline float bf2f(unsigned short b) {
  union { unsigned u; float f; } v; v.u = (unsigned)b << 16; return v.f;
}

__device__ inline void gld_lds16(const void* gptr, void* lptr) {
  __builtin_amdgcn_global_load_lds(
      (const __attribute__((address_space(1))) void*)(uintptr_t)gptr,
      (__attribute__((address_space(3))) void*)(uintptr_t)lptr,
      16, 0, 0);
}

// ---------------- f32 -> bf16 conversion (weights) ----------------
__global__ __launch_bounds__(256) void cvt_kernel(const float* __restrict__ src,
                                                  unsigned short* __restrict__ dst,
                                                  int n4) {
  int i = blockIdx.x * 256 + threadIdx.x;
  int stride = gridDim.x * 256;
  for (; i < n4; i += stride) {
    float4 v = reinterpret_cast<const float4*>(src)[i];
    ushort4 o;
    o.x = f2bf(v.x); o.y = f2bf(v.y); o.z = f2bf(v.z); o.w = f2bf(v.w);
    reinterpret_cast<ushort4*>(dst)[i] = o;
  }
}

// ---------------- router: logits, top-2, softmax -> pair/probs (NO atomics) ----------------
__global__ __launch_bounds__(256) void router_kernel(
    const float* __restrict__ tokens, const float* __restrict__ rw,
    unsigned short* __restrict__ tokb, int* __restrict__ pair,
    float* __restrict__ probs) {
  int wid = threadIdx.x >> 6, lane = threadIdx.x & 63;
  int n = blockIdx.x * 4 + wid;
  const float4* trow = (const float4*)(tokens + (size_t)n * HDIM);
  ushort4* tdst = (ushort4*)(tokb + (size_t)n * HDIM);
  float acc[NEXP];
#pragma unroll
  for (int e = 0; e < NEXP; e++) acc[e] = 0.f;
#pragma unroll
  for (int it = 0; it < 4; it++) {
    int c4 = it * 64 + lane;
    float4 tv = trow[c4];
    ushort4 o;
    o.x = f2bf(tv.x); o.y = f2bf(tv.y); o.z = f2bf(tv.z); o.w = f2bf(tv.w);
    tdst[c4] = o;
#pragma unroll
    for (int e = 0; e < NEXP; e++) {
      float4 w = ((const float4*)(rw + e * HDIM))[c4];
      acc[e] += tv.x * w.x + tv.y * w.y + tv.z * w.z + tv.w * w.w;
    }
  }
#pragma unroll
  for (int e = 0; e < NEXP; e++) {
#pragma unroll
    for (int off = 32; off > 0; off >>= 1) acc[e] += __shfl_xor(acc[e], off, 64);
  }
  if (lane == 0) {
    int e0 = 0; float s0 = acc[0];
#pragma unroll
    for (int e = 1; e < NEXP; e++) if (acc[e] > s0) { s0 = acc[e]; e0 = e; }
    int e1 = -1; float s1 = -3.4e38f;
#pragma unroll
    for (int e = 0; e < NEXP; e++) if (e != e0 && acc[e] > s1) { s1 = acc[e]; e1 = e; }
    float z  = expf(s1 - s0);
    float p0 = 1.f / (1.f + z);
    pair[n] = e0 | (e1 << 8);
    probs[2 * n]     = p0;
    probs[2 * n + 1] = z * p0;
  }
}

// ---------------- dispatch: deterministic per-expert compaction via LDS scan ----------------
__global__ __launch_bounds__(1024) void dispatch_kernel(
    const int* __restrict__ pair, int* __restrict__ counts,
    int* __restrict__ rowids) {
  int e = blockIdx.x;
  int t = threadIdx.x;
  __shared__ int sc[1024];
  int p8[8];
  int c = 0;
#pragma unroll
  for (int i = 0; i < 8; i++) {
    p8[i] = pair[t * 8 + i];
    c += ((p8[i] & 255) == e) + (((p8[i] >> 8) & 255) == e);
  }
  sc[t] = c;
  __syncthreads();
  for (int off = 1; off < 1024; off <<= 1) {
    int v = (t >= off) ? sc[t - off] : 0;
    __syncthreads();
    sc[t] += v;
    __syncthreads();
  }
  if (t == 1023) counts[e] = sc[1023];
  int* dst = rowids + e * CAP + (sc[t] - c);
#pragma unroll
  for (int i = 0; i < 8; i++) {
    int n = t * 8 + i;
    if ((p8[i] & 255) == e)        *dst++ = 2 * n;
    if (((p8[i] >> 8) & 255) == e) *dst++ = 2 * n + 1;
  }
}

// ---------------- worklist: compact (expert, rb256) tile descriptors ----------------
__global__ void worklist_kernel(const int* __restrict__ counts, int* __restrict__ wl) {
  if (threadIdx.x == 0) {
    int p = 0;
    for (int e = 0; e < NEXP; e++) {
      int nt = (counts[e] + 255) >> 8;
      for (int i = 0; i < nt; i++) { wl[1 + p] = (e << 16) | i; p++; }
    }
    wl[0] = p;
  }
}

// ------- gathered NT bf16 GEMM: 256x256 tile, BK=64, single 64KB buffer, 2 blocks/CU -------
// MODE 0 = fc1(+gelu -> Hbuf bf16), MODE 1 = fc2(+bias, *prob -> Ybuf bf16)
template <int MODE>
__global__ __launch_bounds__(512, 4) void moe_gemm(
    const unsigned short* __restrict__ Abase,
    const unsigned short* __restrict__ Wb,
    const float* __restrict__ bias,
    const int* __restrict__ counts, const int* __restrict__ rowids,
    const int* __restrict__ wl, const float* __restrict__ probs,
    unsigned short* __restrict__ dstbuf) {
  constexpr int CB   = MODE ? 4 : 8;       // 256-col blocks over N
  constexpr int KT   = MODE ? 32 : 16;     // K / 64
  constexpr int NCOL = MODE ? 1024 : 2048;
  constexpr int KDIM = MODE ? 2048 : 1024;

  int tile = blockIdx.x / CB;              // consecutive bids share A-panel
  int cb   = blockIdx.x % CB;
  if (tile >= wl[0]) return;
  int d  = wl[1 + tile];
  int e  = d >> 16;
  int rb = d & 0xffff;                     // in 256-row units
  int ce = counts[e];
  const int* rl = rowids + e * CAP + rb * 256;

  int t = threadIdx.x;
  // single buffer: A[256][64]bf16 (32 KB) @0, B[256][64] @32768  => 2 blocks/CU
  __shared__ __align__(16) char smem[65536];

  // staging: chunk c = i*512+t -> LDS byte c*16 (linear); row=c>>3, phys col-chunk=c&7
  // read swizzle j_phys = j ^ (row&7) => source logical chunk jsrc = (t&7)^((t>>3)&7)
  int jsrc = (t & 7) ^ ((t >> 3) & 7);
  const char* asrc[4];
  const char* bsrc[4];
#pragma unroll
  for (int i = 0; i < 4; i++) {
    int r = i * 64 + (t >> 3);
    int rid = (rb * 256 + r < ce) ? rl[r] : rl[0];   // clamp tail to a valid row
    long arow = MODE ? (long)rid : (long)(rid >> 1);
    asrc[i] = (const char*)(Abase + arow * KDIM) + jsrc * 16;
    bsrc[i] = (const char*)(Wb + ((long)e * NCOL + cb * 256 + r) * KDIM) + jsrc * 16;
  }

  auto stage = [&](int kt) {
#pragma unroll
    for (int i = 0; i < 4; i++)
      gld_lds16(asrc[i] + kt * 128, smem + i * 8192 + t * 16);
#pragma unroll
    for (int i = 0; i < 4; i++)
      gld_lds16(bsrc[i] + kt * 128, smem + 32768 + i * 8192 + t * 16);
  };

  f32x4 acc[8][4];
#pragma unroll
  for (int mi = 0; mi < 8; mi++)
#pragma unroll
    for (int ni = 0; ni < 4; ni++) {
      f32x4 z = {0.f, 0.f, 0.f, 0.f};
      acc[mi][ni] = z;
    }

  int lane = t & 63, wid = t >> 6;
  int wr = wid >> 2, wc = wid & 3;   // 2x4 wave grid; per-wave 128 rows x 64 cols
  int lr = lane >> 4, lc = lane & 15;

  for (int kt = 0; kt < KT; kt++) {
    stage(kt);
    __syncthreads();                 // drains vmcnt: tile landed (2nd resident block overlaps)
#pragma unroll
    for (int ks = 0; ks < 2; ks++) {
      bf16x8 af[8], bfv[4];
      int j = ks * 4 + lr;
#pragma unroll
      for (int mi = 0; mi < 8; mi++) {
        int r = wr * 128 + mi * 16 + lc;
        af[mi] = *(const bf16x8*)(smem + r * 128 + ((j ^ (r & 7)) * 16));
      }
#pragma unroll
      for (int ni = 0; ni < 4; ni++) {
        int r = wc * 64 + ni * 16 + lc;
        bfv[ni] = *(const bf16x8*)(smem + 32768 + r * 128 + ((j ^ (r & 7)) * 16));
      }
      __builtin_amdgcn_s_setprio(1);
#pragma unroll
      for (int mi = 0; mi < 8; mi++)
#pragma unroll
        for (int ni = 0; ni < 4; ni++)
          acc[mi][ni] = __builtin_amdgcn_mfma_f32_16x16x32_bf16(af[mi], bfv[ni], acc[mi][ni], 0, 0, 0);
      __builtin_amdgcn_s_setprio(0);
    }
    __syncthreads();                 // all reads of this buf done before next stage
  }

  // ---- epilogue: C = 256x256 bf16 = 128 KB -> two 64 KB halves through smem ----
  float bcol[4];
#pragma unroll
  for (int ni = 0; ni < 4; ni++)
    bcol[ni] = bias[e * NCOL + cb * 256 + wc * 64 + ni * 16 + lc];

#pragma unroll
  for (int h = 0; h < 2; h++) {
    if (wr == h) {
      // this half's waves write their 128x256 C-half, chunk-swizzled
#pragma unroll
      for (int mi = 0; mi < 8; mi++) {
#pragma unroll
        for (int r4 = 0; r4 < 4; r4++) {
          int lrow = mi * 16 + lr * 4 + r4;          // 0..127 within half
          int grow = h * 128 + lrow;
          float p = 1.f;
          if constexpr (MODE == 1)
            p = (rb * 256 + grow < ce) ? probs[rl[grow]] : 0.f;
#pragma unroll
          for (int ni = 0; ni < 4; ni++) {
            int col = wc * 64 + ni * 16 + lc;
            float x = acc[mi][ni][r4] + bcol[ni];
            if constexpr (MODE == 0)
              x = 0.5f * x * (1.f + erff(x * 0.70710678118654752f));  // exact gelu
            else
              x *= p;
            int j = col >> 3;   // 16B chunk within 512B row; swizzle vs row
            *(unsigned short*)(smem + lrow * 512 + ((j ^ (lrow & 31)) << 4) + (col & 7) * 2) = f2bf(x);
          }
        }
      }
    }
    __syncthreads();
    // cooperative store of this half: 4 threads/row, 128B each
    int row = t >> 2, q = t & 3;
    int grow = h * 128 + row;
    if (rb * 256 + grow < ce) {
      int rid = rl[grow];
      char* dst = (char*)(dstbuf + (long)rid * NCOL + cb * 256) + q * 128;
#pragma unroll
      for (int i = 0; i < 8; i++) {
        int j = q * 8 + i;
        *(int4*)(dst + i * 16) = *(const int4*)(smem + row * 512 + ((j ^ (row & 31)) << 4));
      }
    }
    __syncthreads();   // half h fully read before half h+1 overwrites
  }
}

// ---------------- merge: out[n] = Y[2n] + Y[2n+1]  (bf16 -> f32) ----------------
typedef short short8v __attribute__((ext_vector_type(8)));
__global__ __launch_bounds__(256) void merge_kernel(const unsigned short* __restrict__ Y,
                                                    float* __restrict__ out) {
  int i = blockIdx.x * 256 + threadIdx.x;   // 1M chunks of 8 elems
  int n = i >> 7, c = (i & 127) * 8;
  const short8v a = *(const short8v*)(Y + (long)(2 * n) * HDIM + c);
  const short8v b = *(const short8v*)(Y + (long)(2 * n + 1) * HDIM + c);
  float4 o0, o1;
#pragma unroll
  for (int k = 0; k < 8; k++) {
    float v = bf2f((unsigned short)a[k]) + bf2f((unsigned short)b[k]);
    if (k < 4) (&o0.x)[k] = v; else (&o1.x)[k - 4] = v;
  }
  float4* dst = (float4*)(out + (long)n * HDIM + c);
  dst[0] = o0; dst[1] = o1;
}

extern "C" void kernel_launch(void* const* d_in, const int* in_sizes, int n_in,
                              void* d_out, int out_size, void* d_ws, size_t ws_size,
                              hipStream_t stream) {
  const float* tokens   = (const float*)d_in[0];
  const float* router_w = (const float*)d_in[1];
  const float* w1       = (const float*)d_in[2];
  const float* b1       = (const float*)d_in[3];
  const float* w2       = (const float*)d_in[4];
  const float* b2       = (const float*)d_in[5];
  float* out = (float*)d_out;

  // ws layout (bytes):
  //   0        counts[8]
  //   64       rowids[8][16384] int          (512 KiB)
  //   +512K    probs[16384] f32              (64 KiB)
  //   +64K     pair[8192] int                (32 KiB)
  //   +32K     wl[1+72] int                  (~0.3 KiB)
  //   1 MiB    tokens_bf16 [8192][1024]      (16 MiB)
  //   +16M     w1b [8][2048][1024] bf16      (32 MiB)  <- becomes Ybuf after gemm0
  //   +48M     w2b [8][1024][2048] bf16      (32 MiB)
  //   +80M     Hbuf [16384][2048] bf16       (64 MiB)   total ~145 MiB
  char* ws = (char*)d_ws;
  int*            counts = (int*)ws;
  int*            rowids = (int*)(ws + 64);
  float*          probs  = (float*)(ws + 64 + NEXP * CAP * 4);
  int*            pair   = (int*)(ws + 64 + NEXP * CAP * 4 + N_TOK * 2 * 4);
  int*            wl     = (int*)(ws + 64 + NEXP * CAP * 4 + N_TOK * 2 * 4 + N_TOK * 4);
  unsigned short* tokb   = (unsigned short*)(ws + (1u << 20));
  unsigned short* w1b    = (unsigned short*)(ws + (1u << 20) + 16777216u);
  unsigned short* w2b    = (unsigned short*)(ws + (1u << 20) + 16777216u + 33554432u);
  unsigned short* Hbuf   = (unsigned short*)(ws + (1u << 20) + 16777216u + 67108864u);
  unsigned short* Ybuf   = w1b;  // w1 weights dead after gemm0; 32 MiB = 16384x1024 bf16

  cvt_kernel<<<2048, 256, 0, stream>>>(w1, w1b, NEXP * 2048 * 1024 / 4);
  cvt_kernel<<<2048, 256, 0, stream>>>(w2, w2b, NEXP * 1024 * 2048 / 4);
  router_kernel<<<N_TOK / 4, 256, 0, stream>>>(tokens, router_w, tokb, pair, probs);
  dispatch_kernel<<<NEXP, 1024, 0, stream>>>(pair, counts, rowids);
  worklist_kernel<<<1, 64, 0, stream>>>(counts, wl);
  moe_gemm<0><<<MAXT256 * 8, 512, 0, stream>>>(tokb, w1b, b1, counts, rowids, wl, probs, Hbuf);
  moe_gemm<1><<<MAXT256 * 4, 512, 0, stream>>>(Hbuf, w2b, b2, counts, rowids, wl, probs, Ybuf);
  merge_kernel<<<N_TOK * HDIM / 8 / 256, 256, 0, stream>>>(Ybuf, out);
}

// Round 9
// 320.398 us; speedup vs baseline: 6.9491x; 6.9491x over previous
//
#include <hip/hip_runtime.h>
#include <stdint.h>

#define N_TOK 8192
#define HDIM  1024
#define NEXP  8
#define CAP   16384   // per-expert rowid list capacity
#define MAXTILE 136   // >= sum_e ceil(ce/128) = 128 + 7 max

typedef __bf16 bf16x8 __attribute__((ext_vector_type(8)));
typedef float  f32x4  __attribute__((ext_vector_type(4)));

__device__ inline unsigned short f2bf(float f) {
  union { float f; unsigned u; } v; v.f = f;
  return (unsigned short)((v.u + 0x7fffu + ((v.u >> 16) & 1u)) >> 16);  // RNE
}

__device__ inline float bf2f(unsigned short b) {
  union { unsigned u; float f; } v; v.u = (unsigned)b << 16; return v.f;
}

// tanh-form gelu (max |err| vs exact erf-gelu ~1e-3, far under 2.7e-2 threshold)
__device__ inline float gelu_f(float x) {
  float y = 0.7978845608028654f * (x + 0.044715f * x * x * x);
  y = fminf(fmaxf(y, -15.f), 15.f);
  float t = __expf(2.f * y);
  return 0.5f * x * (1.f + (t - 1.f) / (t + 1.f));
}

__device__ inline void gld_lds16(const void* gptr, void* lptr) {
  __builtin_amdgcn_global_load_lds(
      (const __attribute__((address_space(1))) void*)(uintptr_t)gptr,
      (__attribute__((address_space(3))) void*)(uintptr_t)lptr,
      16, 0, 0);
}

// ---------------- f32 -> bf16 conversion (weights) ----------------
__global__ __launch_bounds__(256) void cvt_kernel(const float* __restrict__ src,
                                                  unsigned short* __restrict__ dst,
                                                  int n4) {
  int i = blockIdx.x * 256 + threadIdx.x;
  int stride = gridDim.x * 256;
  for (; i < n4; i += stride) {
    float4 v = reinterpret_cast<const float4*>(src)[i];
    ushort4 o;
    o.x = f2bf(v.x); o.y = f2bf(v.y); o.z = f2bf(v.z); o.w = f2bf(v.w);
    reinterpret_cast<ushort4*>(dst)[i] = o;
  }
}

// ---------------- router: logits, top-2, softmax -> pair/probs (NO atomics) ----------------
__global__ __launch_bounds__(256) void router_kernel(
    const float* __restrict__ tokens, const float* __restrict__ rw,
    unsigned short* __restrict__ tokb, int* __restrict__ pair,
    float* __restrict__ probs) {
  int wid = threadIdx.x >> 6, lane = threadIdx.x & 63;
  int n = blockIdx.x * 4 + wid;
  const float4* trow = (const float4*)(tokens + (size_t)n * HDIM);
  ushort4* tdst = (ushort4*)(tokb + (size_t)n * HDIM);
  float acc[NEXP];
#pragma unroll
  for (int e = 0; e < NEXP; e++) acc[e] = 0.f;
#pragma unroll
  for (int it = 0; it < 4; it++) {
    int c4 = it * 64 + lane;
    float4 tv = trow[c4];
    ushort4 o;
    o.x = f2bf(tv.x); o.y = f2bf(tv.y); o.z = f2bf(tv.z); o.w = f2bf(tv.w);
    tdst[c4] = o;
#pragma unroll
    for (int e = 0; e < NEXP; e++) {
      float4 w = ((const float4*)(rw + e * HDIM))[c4];
      acc[e] += tv.x * w.x + tv.y * w.y + tv.z * w.z + tv.w * w.w;
    }
  }
#pragma unroll
  for (int e = 0; e < NEXP; e++) {
#pragma unroll
    for (int off = 32; off > 0; off >>= 1) acc[e] += __shfl_xor(acc[e], off, 64);
  }
  if (lane == 0) {
    int e0 = 0; float s0 = acc[0];
#pragma unroll
    for (int e = 1; e < NEXP; e++) if (acc[e] > s0) { s0 = acc[e]; e0 = e; }
    int e1 = -1; float s1 = -3.4e38f;
#pragma unroll
    for (int e = 0; e < NEXP; e++) if (e != e0 && acc[e] > s1) { s1 = acc[e]; e1 = e; }
    float z  = expf(s1 - s0);
    float p0 = 1.f / (1.f + z);
    pair[n] = e0 | (e1 << 8);
    probs[2 * n]     = p0;
    probs[2 * n + 1] = z * p0;
  }
}

// ---------------- dispatch: deterministic per-expert compaction via LDS scan ----------------
__global__ __launch_bounds__(1024) void dispatch_kernel(
    const int* __restrict__ pair, int* __restrict__ counts,
    int* __restrict__ rowids) {
  int e = blockIdx.x;
  int t = threadIdx.x;
  __shared__ int sc[1024];
  int p8[8];
  int c = 0;
#pragma unroll
  for (int i = 0; i < 8; i++) {
    p8[i] = pair[t * 8 + i];
    c += ((p8[i] & 255) == e) + (((p8[i] >> 8) & 255) == e);
  }
  sc[t] = c;
  __syncthreads();
  for (int off = 1; off < 1024; off <<= 1) {
    int v = (t >= off) ? sc[t - off] : 0;
    __syncthreads();
    sc[t] += v;
    __syncthreads();
  }
  if (t == 1023) counts[e] = sc[1023];
  int* dst = rowids + e * CAP + (sc[t] - c);
#pragma unroll
  for (int i = 0; i < 8; i++) {
    int n = t * 8 + i;
    if ((p8[i] & 255) == e)        *dst++ = 2 * n;
    if (((p8[i] >> 8) & 255) == e) *dst++ = 2 * n + 1;
  }
}

// ---------------- worklist: compact (expert, rb) tile descriptors ----------------
__global__ void worklist_kernel(const int* __restrict__ counts, int* __restrict__ wl) {
  if (threadIdx.x == 0) {
    int p = 0;
    for (int e = 0; e < NEXP; e++) {
      int nt = (counts[e] + 127) >> 7;
      for (int i = 0; i < nt; i++) { wl[1 + p] = (e << 16) | i; p++; }
    }
    wl[0] = p;
  }
}

// ------- gathered NT bf16 GEMM: 128x128 tile, BK=128, cb->XCD pinned, swizzled epilogue -----
// MODE 0 = fc1(+gelu -> Hbuf bf16), MODE 1 = fc2(+bias, *prob -> Ybuf bf16)
// blockIdx&7 selects the B column-slice (pinned to one XCD): that XCD's 4 MiB L2 holds
// exactly the 8 experts' B-rows for its slice -> B staging is L2-local.
template <int MODE>
__global__ __launch_bounds__(256) void moe_gemm(
    const unsigned short* __restrict__ Abase,
    const unsigned short* __restrict__ Wb,
    const float* __restrict__ bias,
    const int* __restrict__ counts, const int* __restrict__ rowids,
    const int* __restrict__ wl, const float* __restrict__ probs,
    unsigned short* __restrict__ dstbuf) {
  constexpr int KT   = MODE ? 16 : 8;      // K / 128
  constexpr int NCOL = MODE ? 1024 : 2048;
  constexpr int KDIM = MODE ? 2048 : 1024;

  int s = blockIdx.x & 7;                  // XCD pin: B column-slice id
  int r = blockIdx.x >> 3;
  int tile, cb;
  if constexpr (MODE == 0) {               // CB=16: cb = (r&1)*8 + s
    tile = r >> 1;
    cb   = ((r & 1) << 3) + s;
  } else {                                 // CB=8: cb = s
    tile = r;
    cb   = s;
  }
  if (tile >= wl[0]) return;
  int d  = wl[1 + tile];
  int e  = d >> 16;
  int rb = d & 0xffff;
  int ce = counts[e];
  const int* rl = rowids + e * CAP + rb * 128;

  int t = threadIdx.x;
  __shared__ __align__(16) char smem[65536];  // A[128][128]bf16 @0, B @32768

  // LDS chunk c = i*256+t -> byte c*16; row = c>>4, phys col-chunk jp = c&15 (=t&15).
  // Read swizzle jp = j ^ (r&15)  =>  staging source logical chunk
  // jsrc = (t&15) ^ ((t>>4)&15)
  int jsrc = (t & 15) ^ ((t >> 4) & 15);
  const char* asrc[8];
  const char* bsrc[8];
#pragma unroll
  for (int i = 0; i < 8; i++) {
    int rr = i * 16 + (t >> 4);
    int rid = (rb * 128 + rr < ce) ? rl[rr] : rl[0];   // clamp tail to a valid row
    long arow = MODE ? (long)rid : (long)(rid >> 1);
    asrc[i] = (const char*)(Abase + arow * KDIM) + jsrc * 16;
    bsrc[i] = (const char*)(Wb + ((long)e * NCOL + cb * 128 + rr) * KDIM) + jsrc * 16;
  }

  f32x4 acc[4][4];
#pragma unroll
  for (int mi = 0; mi < 4; mi++)
#pragma unroll
    for (int ni = 0; ni < 4; ni++) {
      f32x4 z = {0.f, 0.f, 0.f, 0.f};
      acc[mi][ni] = z;
    }

  int lane = t & 63, wid = t >> 6;
  int wr = wid >> 1, wc = wid & 1;        // 2x2 wave grid, 64x64 per wave
  int lr = lane >> 4, lc = lane & 15;

  for (int kt = 0; kt < KT; kt++) {
#pragma unroll
    for (int i = 0; i < 8; i++)
      gld_lds16(asrc[i] + kt * 256, smem + i * 4096 + t * 16);
#pragma unroll
    for (int i = 0; i < 8; i++)
      gld_lds16(bsrc[i] + kt * 256, smem + 32768 + i * 4096 + t * 16);
    __syncthreads();
#pragma unroll
    for (int ks = 0; ks < 4; ks++) {
      bf16x8 af[4], bfr[4];
      int j = ks * 4 + lr;
#pragma unroll
      for (int mi = 0; mi < 4; mi++) {
        int rr = wr * 64 + mi * 16 + lc;
        af[mi] = *(const bf16x8*)(smem + rr * 256 + ((j ^ (rr & 15)) * 16));
      }
#pragma unroll
      for (int ni = 0; ni < 4; ni++) {
        int rr = wc * 64 + ni * 16 + lc;
        bfr[ni] = *(const bf16x8*)(smem + 32768 + rr * 256 + ((j ^ (rr & 15)) * 16));
      }
      __builtin_amdgcn_s_setprio(1);
#pragma unroll
      for (int mi = 0; mi < 4; mi++)
#pragma unroll
        for (int ni = 0; ni < 4; ni++)
          acc[mi][ni] = __builtin_amdgcn_mfma_f32_16x16x32_bf16(af[mi], bfr[ni], acc[mi][ni], 0, 0, 0);
      __builtin_amdgcn_s_setprio(0);
    }
    __syncthreads();
  }

  // ---- epilogue: stage C (128x128 bf16 = 32 KB) in smem, chunk-swizzled, 16B stores ----
  float bcol[4];
#pragma unroll
  for (int ni = 0; ni < 4; ni++)
    bcol[ni] = bias[e * NCOL + cb * 128 + wc * 64 + ni * 16 + lc];

#pragma unroll
  for (int mi = 0; mi < 4; mi++) {
#pragma unroll
    for (int r4 = 0; r4 < 4; r4++) {
      int lrow = wr * 64 + mi * 16 + lr * 4 + r4;
      float p = 1.f;
      if constexpr (MODE == 1)
        p = (rb * 128 + lrow < ce) ? probs[rl[lrow]] : 0.f;
#pragma unroll
      for (int ni = 0; ni < 4; ni++) {
        int col = wc * 64 + ni * 16 + lc;
        float x = acc[mi][ni][r4] + bcol[ni];
        if constexpr (MODE == 0)
          x = gelu_f(x);
        else
          x *= p;
        int j = col >> 3;   // 16B chunk within 256B row; swizzle vs row
        *(unsigned short*)(smem + lrow * 256 + ((j ^ (lrow & 15)) << 4) + (col & 7) * 2) = f2bf(x);
      }
    }
  }
  __syncthreads();

  int row = t >> 1, h = t & 1;   // 2 threads/row, 128B each
  if (rb * 128 + row < ce) {
    int rid = rl[row];
    char* dst = (char*)(dstbuf + (long)rid * NCOL + cb * 128) + h * 128;
#pragma unroll
    for (int i = 0; i < 8; i++) {
      int j = h * 8 + i;
      *(int4*)(dst + i * 16) = *(const int4*)(smem + row * 256 + ((j ^ (row & 15)) << 4));
    }
  }
}

// ---------------- merge: out[n] = Y[2n] + Y[2n+1]  (bf16 -> f32) ----------------
typedef short short8v __attribute__((ext_vector_type(8)));
__global__ __launch_bounds__(256) void merge_kernel(const unsigned short* __restrict__ Y,
                                                    float* __restrict__ out) {
  int i = blockIdx.x * 256 + threadIdx.x;   // 1M chunks of 8 elems
  int n = i >> 7, c = (i & 127) * 8;
  const short8v a = *(const short8v*)(Y + (long)(2 * n) * HDIM + c);
  const short8v b = *(const short8v*)(Y + (long)(2 * n + 1) * HDIM + c);
  float4 o0, o1;
#pragma unroll
  for (int k = 0; k < 8; k++) {
    float v = bf2f((unsigned short)a[k]) + bf2f((unsigned short)b[k]);
    if (k < 4) (&o0.x)[k] = v; else (&o1.x)[k - 4] = v;
  }
  float4* dst = (float4*)(out + (long)n * HDIM + c);
  dst[0] = o0; dst[1] = o1;
}

extern "C" void kernel_launch(void* const* d_in, const int* in_sizes, int n_in,
                              void* d_out, int out_size, void* d_ws, size_t ws_size,
                              hipStream_t stream) {
  const float* tokens   = (const float*)d_in[0];
  const float* router_w = (const float*)d_in[1];
  const float* w1       = (const float*)d_in[2];
  const float* b1       = (const float*)d_in[3];
  const float* w2       = (const float*)d_in[4];
  const float* b2       = (const float*)d_in[5];
  float* out = (float*)d_out;

  // ws layout (bytes):
  //   0        counts[8]
  //   64       rowids[8][16384] int          (512 KiB)
  //   +512K    probs[16384] f32              (64 KiB)
  //   +64K     pair[8192] int                (32 KiB)
  //   +32K     wl[1+136] int                 (~1 KiB)
  //   1 MiB    tokens_bf16 [8192][1024]      (16 MiB)
  //   +16M     w1b [8][2048][1024] bf16      (32 MiB)  <- becomes Ybuf after gemm0
  //   +48M     w2b [8][1024][2048] bf16      (32 MiB)
  //   +80M     Hbuf [16384][2048] bf16       (64 MiB)   total ~145 MiB
  char* ws = (char*)d_ws;
  int*            counts = (int*)ws;
  int*            rowids = (int*)(ws + 64);
  float*          probs  = (float*)(ws + 64 + NEXP * CAP * 4);
  int*            pair   = (int*)(ws + 64 + NEXP * CAP * 4 + N_TOK * 2 * 4);
  int*            wl     = (int*)(ws + 64 + NEXP * CAP * 4 + N_TOK * 2 * 4 + N_TOK * 4);
  unsigned short* tokb   = (unsigned short*)(ws + (1u << 20));
  unsigned short* w1b    = (unsigned short*)(ws + (1u << 20) + 16777216u);
  unsigned short* w2b    = (unsigned short*)(ws + (1u << 20) + 16777216u + 33554432u);
  unsigned short* Hbuf   = (unsigned short*)(ws + (1u << 20) + 16777216u + 67108864u);
  unsigned short* Ybuf   = w1b;  // w1 weights dead after gemm0; 32 MiB = 16384x1024 bf16

  cvt_kernel<<<2048, 256, 0, stream>>>(w1, w1b, NEXP * 2048 * 1024 / 4);
  cvt_kernel<<<2048, 256, 0, stream>>>(w2, w2b, NEXP * 1024 * 2048 / 4);
  router_kernel<<<N_TOK / 4, 256, 0, stream>>>(tokens, router_w, tokb, pair, probs);
  dispatch_kernel<<<NEXP, 1024, 0, stream>>>(pair, counts, rowids);
  worklist_kernel<<<1, 64, 0, stream>>>(counts, wl);
  // gemm0: grid = MAXTILE * 2 * 8  (s=bid&7 -> XCD-pinned cb slice; r=bid>>3 -> (tile,half))
  moe_gemm<0><<<MAXTILE * 16, 256, 0, stream>>>(tokb, w1b, b1, counts, rowids, wl, probs, Hbuf);
  // gemm1: grid = MAXTILE * 8    (s=bid&7 -> cb; tile=bid>>3)
  moe_gemm<1><<<MAXTILE * 8, 256, 0, stream>>>(Hbuf, w2b, b2, counts, rowids, wl, probs, Ybuf);
  merge_kernel<<<N_TOK * HDIM / 8 / 256, 256, 0, stream>>>(Ybuf, out);
}